// Round 1
// baseline (142.450 us; speedup 1.0000x reference)
//
#include <hip/hip_runtime.h>
#include <math.h>

#define K_BR 4
#define B_SZ 8
#define T_SZ 2048
#define C_SZ 1024
#define HID  256
#define EPSF 1e-6f

// ---------------------------------------------------------------------------
// Kernel 1: partial mean over T.
// grid = tseg * (B*K) blocks, 256 threads. Each block sums a T-chunk of one
// (b,k) slice, float4-vectorized over C. Writes partial[seg][b*K+k][C].
// ---------------------------------------------------------------------------
__global__ void pool_partial(const float* __restrict__ br,
                             float* __restrict__ part,
                             int tchunk) {
    int chunk = blockIdx.x & 31;   // b*K + k in [0,32)
    int seg   = blockIdx.x >> 5;
    int b = chunk >> 2;
    int k = chunk & 3;
    int t0 = seg * tchunk;

    const float4* src = (const float4*)(br + (size_t)(k * B_SZ + b) * T_SZ * C_SZ);
    int c4 = threadIdx.x;          // 0..255 covers C/4
    float4 acc = make_float4(0.f, 0.f, 0.f, 0.f);
    for (int t = t0; t < t0 + tchunk; ++t) {
        float4 v = src[(size_t)t * (C_SZ / 4) + c4];
        acc.x += v.x; acc.y += v.y; acc.z += v.z; acc.w += v.w;
    }
    float4* dst = (float4*)(part + ((size_t)seg * 32 + chunk) * C_SZ);
    dst[c4] = acc;
}

// ---------------------------------------------------------------------------
// Kernel 2: finish pooling, h = tanh(pooled @ w_proj^T), logits = h @ w_out^T.
// grid = 32 blocks (one per b,k), 256 threads (= HIDDEN).
// ---------------------------------------------------------------------------
__global__ void proj_logits(const float* __restrict__ part,
                            const float* __restrict__ w_proj,
                            const float* __restrict__ w_out,
                            float* __restrict__ logits,
                            int tseg) {
    __shared__ float pooled[C_SZ];
    __shared__ float red[4];
    int chunk = blockIdx.x;        // b*K + k
    int tid = threadIdx.x;

    // reduce partials: each thread owns 4 consecutive c's
    float4 acc = make_float4(0.f, 0.f, 0.f, 0.f);
    for (int seg = 0; seg < tseg; ++seg) {
        const float4* p = (const float4*)(part + ((size_t)seg * 32 + chunk) * C_SZ);
        float4 v = p[tid];
        acc.x += v.x; acc.y += v.y; acc.z += v.z; acc.w += v.w;
    }
    const float inv = 1.0f / (float)T_SZ;
    ((float4*)pooled)[tid] = make_float4(acc.x * inv, acc.y * inv, acc.z * inv, acc.w * inv);
    __syncthreads();

    // dot(pooled, w_proj[tid,:])
    const float4* wrow = (const float4*)(w_proj + (size_t)tid * C_SZ);
    const float4* pl   = (const float4*)pooled;
    float dot = 0.f;
#pragma unroll 8
    for (int c4 = 0; c4 < C_SZ / 4; ++c4) {
        float4 w = wrow[c4];
        float4 p = pl[c4];
        dot += w.x * p.x + w.y * p.y + w.z * p.z + w.w * p.w;
    }
    float hv = tanhf(dot) * w_out[tid];

    // block reduce (4 waves of 64)
    for (int off = 32; off > 0; off >>= 1)
        hv += __shfl_down(hv, off, 64);
    if ((tid & 63) == 0) red[tid >> 6] = hv;
    __syncthreads();
    if (tid == 0)
        logits[chunk] = red[0] + red[1] + red[2] + red[3];
}

// ---------------------------------------------------------------------------
// Kernel 3: Sinkhorn on 4x4 per batch, produce normalized weights (B,K).
// 1 block, thread b handles batch b.
// ---------------------------------------------------------------------------
__global__ void sinkhorn_weights(const float* __restrict__ logits,
                                 float* __restrict__ weights) {
    int b = threadIdx.x;
    if (b >= B_SZ) return;
    float L[4];
#pragma unroll
    for (int i = 0; i < 4; ++i) L[i] = logits[b * 4 + i];
    float mx = fmaxf(fmaxf(L[0], L[1]), fmaxf(L[2], L[3]));
    float m = 2.0f * mx;   // max over i,j of L[i]+L[j]
    float t[4][4];
#pragma unroll
    for (int i = 0; i < 4; ++i)
#pragma unroll
        for (int j = 0; j < 4; ++j)
            t[i][j] = fmaxf(expf(L[i] + L[j] - m), EPSF);

#pragma unroll
    for (int it = 0; it < 5; ++it) {
#pragma unroll
        for (int i = 0; i < 4; ++i) {
            float rs = t[i][0] + t[i][1] + t[i][2] + t[i][3] + EPSF;
#pragma unroll
            for (int j = 0; j < 4; ++j) t[i][j] /= rs;
        }
#pragma unroll
        for (int j = 0; j < 4; ++j) {
            float cs = t[0][j] + t[1][j] + t[2][j] + t[3][j] + EPSF;
#pragma unroll
            for (int i = 0; i < 4; ++i) t[i][j] /= cs;
        }
    }
#pragma unroll
    for (int i = 0; i < 4; ++i) {
        float rs = t[i][0] + t[i][1] + t[i][2] + t[i][3] + EPSF;
#pragma unroll
        for (int j = 0; j < 4; ++j) t[i][j] /= rs;
    }
    float w[4];
#pragma unroll
    for (int j = 0; j < 4; ++j)
        w[j] = 0.25f * (t[0][j] + t[1][j] + t[2][j] + t[3][j]);
    float s = w[0] + w[1] + w[2] + w[3] + EPSF;
#pragma unroll
    for (int j = 0; j < 4; ++j) w[j] /= s;
    bool fin = isfinite(w[0]) && isfinite(w[1]) && isfinite(w[2]) && isfinite(w[3]);
#pragma unroll
    for (int j = 0; j < 4; ++j)
        weights[b * 4 + j] = fin ? w[j] : 0.25f;
}

// ---------------------------------------------------------------------------
// Kernel 4: mixed[b,t,c] = sum_k weights[b,k] * branches[k,b,t,c]
// float4 grid-stride.
// ---------------------------------------------------------------------------
__global__ void mix_kernel(const float* __restrict__ br,
                           const float* __restrict__ weights,
                           float* __restrict__ out) {
    const size_t n4total = (size_t)B_SZ * T_SZ * C_SZ / 4;   // 4,194,304
    const size_t btc4 = (size_t)T_SZ * C_SZ / 4;             // 524,288 = 2^19
    const float4* src = (const float4*)br;
    float4* dst = (float4*)out;
    for (size_t n = (size_t)blockIdx.x * blockDim.x + threadIdx.x;
         n < n4total;
         n += (size_t)gridDim.x * blockDim.x) {
        int b = (int)(n >> 19);
        size_t r = n & (btc4 - 1);
        float w0 = weights[b * 4 + 0];
        float w1 = weights[b * 4 + 1];
        float w2 = weights[b * 4 + 2];
        float w3 = weights[b * 4 + 3];
        float4 v0 = src[((size_t)(0 * B_SZ + b)) * btc4 + r];
        float4 v1 = src[((size_t)(1 * B_SZ + b)) * btc4 + r];
        float4 v2 = src[((size_t)(2 * B_SZ + b)) * btc4 + r];
        float4 v3 = src[((size_t)(3 * B_SZ + b)) * btc4 + r];
        float4 o;
        o.x = w0 * v0.x + w1 * v1.x + w2 * v2.x + w3 * v3.x;
        o.y = w0 * v0.y + w1 * v1.y + w2 * v2.y + w3 * v3.y;
        o.z = w0 * v0.z + w1 * v1.z + w2 * v2.z + w3 * v3.z;
        o.w = w0 * v0.w + w1 * v1.w + w2 * v2.w + w3 * v3.w;
        dst[n] = o;
    }
}

extern "C" void kernel_launch(void* const* d_in, const int* in_sizes, int n_in,
                              void* d_out, int out_size, void* d_ws, size_t ws_size,
                              hipStream_t stream) {
    const float* branches = (const float*)d_in[0];
    const float* w_proj   = (const float*)d_in[1];
    const float* w_out    = (const float*)d_in[2];
    float* out = (float*)d_out;
    float* ws  = (float*)d_ws;

    // choose T-segmentation to fit workspace: need tseg*32*C floats + 64
    int tseg = 32;
    while (tseg > 1 &&
           ((size_t)tseg * 32 * C_SZ + 64) * sizeof(float) > ws_size)
        tseg >>= 1;
    int tchunk = T_SZ / tseg;

    float* part       = ws;
    float* logits_ws  = ws + (size_t)tseg * 32 * C_SZ;
    float* weights_ws = logits_ws + 32;

    pool_partial<<<tseg * 32, 256, 0, stream>>>(branches, part, tchunk);
    proj_logits<<<32, 256, 0, stream>>>(part, w_proj, w_out, logits_ws, tseg);
    sinkhorn_weights<<<1, 64, 0, stream>>>(logits_ws, weights_ws);
    mix_kernel<<<2048, 256, 0, stream>>>(branches, weights_ws, out);
}

// Round 3
// 111.710 us; speedup vs baseline: 1.2752x; 1.2752x over previous
//
#include <hip/hip_runtime.h>
#include <math.h>

#define K_BR 4
#define B_SZ 8
#define T_SZ 2048
#define C_SZ 1024
#define HID  256
#define EPSF 1e-6f

typedef float f32x4 __attribute__((ext_vector_type(4)));

// ---------------------------------------------------------------------------
// Kernel 1: partial mean over T.
// grid = tseg * 32 blocks, 256 threads. Each block sums a T-chunk of one
// (b,k) slice, float4-vectorized over C. Writes part[seg][b*4+k][C].
// ---------------------------------------------------------------------------
__global__ void pool_partial(const float* __restrict__ br,
                             float* __restrict__ part,
                             int tchunk) {
    int chunk = blockIdx.x & 31;   // b*4 + k
    int seg   = blockIdx.x >> 5;
    int b = chunk >> 2;
    int k = chunk & 3;
    int t0 = seg * tchunk;

    const f32x4* src = (const f32x4*)(br + (size_t)(k * B_SZ + b) * T_SZ * C_SZ);
    int c4 = threadIdx.x;          // 0..255 covers C/4
    f32x4 acc = (f32x4)(0.f);
#pragma unroll 4
    for (int t = t0; t < t0 + tchunk; ++t) {
        acc += src[(size_t)t * (C_SZ / 4) + c4];
    }
    f32x4* dst = (f32x4*)(part + ((size_t)seg * 32 + chunk) * C_SZ);
    dst[c4] = acc;
}

// ---------------------------------------------------------------------------
// Kernel 2: finish pooling + h = tanh(pooled @ w_proj^T) * w_out, partial
// logits. grid = 256 blocks: (chunk = bid>>3, hgroup = bid&7). Each block
// handles 32 hidden rows; 8 lanes per row (128 c each), shfl_xor reduce.
// Writes logits_part[chunk*8 + hgroup]. Fully deterministic.
// ---------------------------------------------------------------------------
__global__ void proj_logits(const float* __restrict__ part,
                            const float* __restrict__ w_proj,
                            const float* __restrict__ w_out,
                            float* __restrict__ logits_part,
                            int tseg) {
    __shared__ float pooled[C_SZ];
    __shared__ float red[32];
    int bid   = blockIdx.x;
    int chunk = bid >> 3;          // b*4 + k
    int hg    = bid & 7;           // hidden group
    int tid   = threadIdx.x;

    // seg-reduce partials: thread tid owns float4 column tid
    f32x4 acc = (f32x4)(0.f);
    for (int seg = 0; seg < tseg; ++seg) {
        acc += ((const f32x4*)(part + ((size_t)seg * 32 + chunk) * C_SZ))[tid];
    }
    const float inv = 1.0f / (float)T_SZ;
    ((f32x4*)pooled)[tid] = acc * inv;
    __syncthreads();

    // 32 rows per block: row h = hg*32 + (tid>>3); lane sub = tid&7 covers 128 c
    int h   = hg * 32 + (tid >> 3);
    int sub = tid & 7;
    const f32x4* wrow = (const f32x4*)(w_proj + (size_t)h * C_SZ);
    const f32x4* pl   = (const f32x4*)pooled;
    float dot = 0.f;
#pragma unroll 8
    for (int j = 0; j < 32; ++j) {
        int c4 = sub * 32 + j;
        f32x4 w = wrow[c4];
        f32x4 p = pl[c4];
        f32x4 m = w * p;
        dot += m.x + m.y + m.z + m.w;
    }
    dot += __shfl_xor(dot, 1, 64);
    dot += __shfl_xor(dot, 2, 64);
    dot += __shfl_xor(dot, 4, 64);
    if (sub == 0) red[tid >> 3] = tanhf(dot) * w_out[h];
    __syncthreads();
    if (tid == 0) {
        float s = 0.f;
        for (int i = 0; i < 32; ++i) s += red[i];
        logits_part[chunk * 8 + hg] = s;
    }
}

// ---------------------------------------------------------------------------
// Kernel 3: reduce partial logits -> sinkhorn weights (in every block's LDS,
// redundant but tiny) -> blend over K with nontemporal stores.
// ---------------------------------------------------------------------------
__global__ void mix_kernel(const float* __restrict__ br,
                           const float* __restrict__ logits_part,
                           float* __restrict__ out) {
    __shared__ float lp[256];
    __shared__ float lg[32];
    __shared__ float wgt[B_SZ][4];
    int tid = threadIdx.x;

    lp[tid] = logits_part[tid];
    __syncthreads();
    if (tid < 32) {
        float s = 0.f;
#pragma unroll
        for (int g = 0; g < 8; ++g) s += lp[tid * 8 + g];
        lg[tid] = s;               // logits[b*4+k]
    }
    __syncthreads();
    if (tid < B_SZ) {
        int b = tid;
        float L[4];
#pragma unroll
        for (int i = 0; i < 4; ++i) L[i] = lg[b * 4 + i];
        float mx = fmaxf(fmaxf(L[0], L[1]), fmaxf(L[2], L[3]));
        float m = 2.0f * mx;
        float t[4][4];
#pragma unroll
        for (int i = 0; i < 4; ++i)
#pragma unroll
            for (int j = 0; j < 4; ++j)
                t[i][j] = fmaxf(expf(L[i] + L[j] - m), EPSF);
#pragma unroll
        for (int it = 0; it < 5; ++it) {
#pragma unroll
            for (int i = 0; i < 4; ++i) {
                float rs = t[i][0] + t[i][1] + t[i][2] + t[i][3] + EPSF;
#pragma unroll
                for (int j = 0; j < 4; ++j) t[i][j] /= rs;
            }
#pragma unroll
            for (int j = 0; j < 4; ++j) {
                float cs = t[0][j] + t[1][j] + t[2][j] + t[3][j] + EPSF;
#pragma unroll
                for (int i = 0; i < 4; ++i) t[i][j] /= cs;
            }
        }
#pragma unroll
        for (int i = 0; i < 4; ++i) {
            float rs = t[i][0] + t[i][1] + t[i][2] + t[i][3] + EPSF;
#pragma unroll
            for (int j = 0; j < 4; ++j) t[i][j] /= rs;
        }
        float w[4];
#pragma unroll
        for (int j = 0; j < 4; ++j)
            w[j] = 0.25f * (t[0][j] + t[1][j] + t[2][j] + t[3][j]);
        float s = w[0] + w[1] + w[2] + w[3] + EPSF;
#pragma unroll
        for (int j = 0; j < 4; ++j) w[j] /= s;
        bool fin = isfinite(w[0]) && isfinite(w[1]) && isfinite(w[2]) && isfinite(w[3]);
#pragma unroll
        for (int j = 0; j < 4; ++j)
            wgt[b][j] = fin ? w[j] : 0.25f;
    }
    __syncthreads();

    const size_t n4total = (size_t)B_SZ * T_SZ * C_SZ / 4;   // 4,194,304
    const size_t btc4 = (size_t)T_SZ * C_SZ / 4;             // 524,288 = 2^19
    const f32x4* src = (const f32x4*)br;
    f32x4* dst = (f32x4*)out;
    for (size_t n = (size_t)blockIdx.x * blockDim.x + tid;
         n < n4total;
         n += (size_t)gridDim.x * blockDim.x) {
        int b = (int)(n >> 19);
        size_t r = n & (btc4 - 1);
        float w0 = wgt[b][0], w1 = wgt[b][1], w2 = wgt[b][2], w3 = wgt[b][3];
        f32x4 v0 = src[((size_t)(0 * B_SZ + b)) * btc4 + r];
        f32x4 v1 = src[((size_t)(1 * B_SZ + b)) * btc4 + r];
        f32x4 v2 = src[((size_t)(2 * B_SZ + b)) * btc4 + r];
        f32x4 v3 = src[((size_t)(3 * B_SZ + b)) * btc4 + r];
        f32x4 o = w0 * v0 + w1 * v1 + w2 * v2 + w3 * v3;
        __builtin_nontemporal_store(o, &dst[n]);
    }
}

extern "C" void kernel_launch(void* const* d_in, const int* in_sizes, int n_in,
                              void* d_out, int out_size, void* d_ws, size_t ws_size,
                              hipStream_t stream) {
    const float* branches = (const float*)d_in[0];
    const float* w_proj   = (const float*)d_in[1];
    const float* w_out    = (const float*)d_in[2];
    float* out = (float*)d_out;
    float* ws  = (float*)d_ws;

    int tseg = 32;
    while (tseg > 1 &&
           ((size_t)tseg * 32 * C_SZ + 256) * sizeof(float) > ws_size)
        tseg >>= 1;
    int tchunk = T_SZ / tseg;

    float* part        = ws;
    float* logits_part = ws + (size_t)tseg * 32 * C_SZ;   // 256 floats

    pool_partial<<<tseg * 32, 256, 0, stream>>>(branches, part, tchunk);
    proj_logits<<<256, 256, 0, stream>>>(part, w_proj, w_out, logits_part, tseg);
    mix_kernel<<<2048, 256, 0, stream>>>(branches, logits_part, out);
}